// Round 7
// baseline (772.472 us; speedup 1.0000x reference)
//
#include <hip/hip_runtime.h>

// MPT attention w/ ALiBi: B=4 S=2048 D=2048 H=16 HD=128, fp32 in/out,
// bf16 MFMA pipeline.
//
// Pipeline:
//   1. transpose_cvt: Wqkv -> WqkvT bf16 [6144][2048], Wout -> WoutT bf16 [2048][2048]
//   2. cvt_bf16: x fp32 -> xb bf16 [8192][2048] (stored in d_out scratch)
//   3. gemm_qkv: qkv = xb @ Wqkv + b ; 256x256x64 tiles, 8 waves, double-buffered
//      LDS, 4-subphase pipelined schedule, vmcnt(0) only at tile boundary.
//      Writes Q,K [B,H,S,HD], V^T [B,H,HD,S].
//   4. attn: flash attention, 512 thr / 8 waves, q-block 128, branch-free inner
//      loop, XCD-clustered grid, setprio around MFMA clusters.
//   5. gemm_out: out = O @ Wout + b_out; 128x256x32 m97-structure, XCD-flat grid.
//
// ws layout (128 MiB): [0) WqkvT 24M ][24M) WoutT 8M ][32M) Q/O 32M ][64M) K 32M ][96M) V^T 32M ]

typedef unsigned short u16;
typedef unsigned int u32;
typedef u16  u16x8 __attribute__((ext_vector_type(8)));
typedef __bf16 bf16x8 __attribute__((ext_vector_type(8)));
typedef float f32x4 __attribute__((ext_vector_type(4)));

__device__ __forceinline__ u16 f2b(float f) {
  union { float f; unsigned u; } v; v.f = f;
  return (u16)((v.u + 0x7fffu + ((v.u >> 16) & 1u)) >> 16);  // RNE
}

// pack two fp32 -> two bf16 (RNE-ish) in one v_perm: [lo16=bf16(a) | hi16=bf16(b)]
__device__ __forceinline__ u32 pk2(float a, float b) {
  u32 ua = __float_as_uint(a) + 0x8000u;
  u32 ub = __float_as_uint(b) + 0x8000u;
  return __builtin_amdgcn_perm(ub, ua, 0x07060302u);
}

__device__ __forceinline__ f32x4 mfma16(bf16x8 a, bf16x8 b, f32x4 c) {
  return __builtin_amdgcn_mfma_f32_16x16x32_bf16(a, b, c, 0, 0, 0);
}
__device__ __forceinline__ bf16x8 ldb(const u16* p) { return *(const bf16x8*)p; }

// async global->LDS, 16B per lane. LDS dest is wave-uniform base + lane*16.
__device__ __forceinline__ void g2l16(const u16* g, u16* l) {
  __builtin_amdgcn_global_load_lds(
      (const __attribute__((address_space(1))) unsigned int*)g,
      (__attribute__((address_space(3))) unsigned int*)l, 16, 0, 0);
}

extern __shared__ u16 dyn_smem[];

// ---------------------------------------------------------------- transpose+cvt
__global__ __launch_bounds__(256) void transpose_cvt(
    const float* __restrict__ src, u16* __restrict__ dst, int R, int C) {
  __shared__ float tile[32][33];
  const int c0 = blockIdx.x * 32, r0 = blockIdx.y * 32;
  const int tx = threadIdx.x & 31, ty = threadIdx.x >> 5;
  #pragma unroll
  for (int i = 0; i < 4; ++i)
    tile[ty + 8 * i][tx] = src[(size_t)(r0 + ty + 8 * i) * C + c0 + tx];
  __syncthreads();
  #pragma unroll
  for (int i = 0; i < 4; ++i)
    dst[(size_t)(c0 + ty + 8 * i) * R + r0 + tx] = f2b(tile[tx][ty + 8 * i]);
}

// ---------------------------------------------------------------- x fp32 -> bf16
__global__ __launch_bounds__(256) void cvt_bf16(
    const float* __restrict__ src, u16* __restrict__ dst) {
  const size_t i = ((size_t)blockIdx.x * 256 + threadIdx.x) * 8;
  f32x4 a = *(const f32x4*)(src + i);
  f32x4 b = *(const f32x4*)(src + i + 4);
  uint4 w;
  w.x = pk2(a[0], a[1]); w.y = pk2(a[2], a[3]);
  w.z = pk2(b[0], b[1]); w.w = pk2(b[2], b[3]);
  *(uint4*)(dst + i) = w;
}

// ---------------------------------------------------------------- GEMM1: QKV proj
// C[8192,6144] = xb @ Wqkv + b. 256x256x64 tiles, 8 waves (2M x 4N), 8x4 frags/wave.
// Double-buffered LDS (2 x (A 256x64 + B 256x64) = 128 KiB dynamic).
// Per K-tile: 4 sub-phases, each {stage 1 half-tile of t+1 | ds_read subtile |
// setprio+16 MFMA | raw s_barrier}. vmcnt(0) ONLY at the tile boundary, so the
// 8 prefetch loads stay in flight across the intra-tile phases.
__global__ __launch_bounds__(512, 2) void gemm_qkv(
    const u16* __restrict__ xb, const u16* __restrict__ wT,
    const float* __restrict__ bias,
    u16* __restrict__ qbuf, u16* __restrict__ kbuf, u16* __restrict__ vbuf) {
  u16* qsm = dyn_smem;  // [c][ A 256*64 | B 256*64 ] u16 ; epilogue: [256][136]
  const int tid = threadIdx.x;
  const int lane = tid & 63, wv = tid >> 6;
  const int L = lane & 15, g = lane >> 4;
  const int wm = (wv >> 2) * 128, wn = (wv & 3) * 64;
  const int bid = (int)blockIdx.x;
  const int wg = (bid & 7) * 96 + (bid >> 3);   // bijective XCD cluster (768 = 8*96)
  const int mt = wg / 24, nt = wg - mt * 24;
  const int m0 = mt * 256, n0 = nt * 256;

  // staging: per thread 2 loads per half-tile (128 rows x 64 cols bf16).
  // load n covers rows h*128 + wv*16 + n*8 + (lane>>3), cols (lane&7)*8.
  const int srow = lane >> 3, scol = (lane & 7) * 8;
  const u16* gA = xb + (size_t)(m0 + wv * 16 + srow) * 2048 + scol;
  const u16* gB = wT + (size_t)(n0 + wv * 16 + srow) * 2048 + scol;
  u16* lA = qsm + wv * 1024;            // + c*32768 + h*8192 (+512 for 2nd load)
  u16* lB = qsm + 16384 + wv * 1024;

#define STAGE_A(c, h, kt) do { \
    const u16* s_ = gA + (size_t)(h) * (128 * 2048) + (kt) * 64; \
    u16* d_ = lA + (c) * 32768 + (h) * 8192; \
    g2l16(s_, d_); g2l16(s_ + (size_t)8 * 2048, d_ + 512); } while (0)
#define STAGE_B(c, h, kt) do { \
    const u16* s_ = gB + (size_t)(h) * (128 * 2048) + (kt) * 64; \
    u16* d_ = lB + (c) * 32768 + (h) * 8192; \
    g2l16(s_, d_); g2l16(s_ + (size_t)8 * 2048, d_ + 512); } while (0)

  f32x4 acc[8][4] = {};

  // prologue: tile 0 -> buf 0 (full drain via __syncthreads)
  STAGE_A(0, 0, 0); STAGE_A(0, 1, 0); STAGE_B(0, 0, 0); STAGE_B(0, 1, 0);
  __syncthreads();

  for (int kt = 0; kt < 32; ++kt) {
    const int c = kt & 1, cn = c ^ 1;
    const int ktn = kt < 31 ? kt + 1 : 31;  // last prefetch redundant, harmless
    const u16* sAc = qsm + c * 32768;
    const u16* sBc = qsm + c * 32768 + 16384;
    bf16x8 a_[4][2], b01[2][2], b23[2][2];

    // ---- phase 0: stage A-half0(t+1); aLo + b01; MFMA quadrant (ti0-3, tj0-1)
    STAGE_A(cn, 0, ktn);
    #pragma unroll
    for (int ti = 0; ti < 4; ++ti)
      #pragma unroll
      for (int ks = 0; ks < 2; ++ks)
        a_[ti][ks] = ldb(&sAc[(wm + 16 * ti + L) * 64 + ks * 32 + 8 * g]);
    #pragma unroll
    for (int tj = 0; tj < 2; ++tj)
      #pragma unroll
      for (int ks = 0; ks < 2; ++ks)
        b01[tj][ks] = ldb(&sBc[(wn + 16 * tj + L) * 64 + ks * 32 + 8 * g]);
    __builtin_amdgcn_s_setprio(1);
    #pragma unroll
    for (int ti = 0; ti < 4; ++ti)
      #pragma unroll
      for (int tj = 0; tj < 2; ++tj) {
        acc[ti][tj] = mfma16(a_[ti][0], b01[tj][0], acc[ti][tj]);
        acc[ti][tj] = mfma16(a_[ti][1], b01[tj][1], acc[ti][tj]);
      }
    __builtin_amdgcn_s_setprio(0);
    __builtin_amdgcn_s_barrier();

    // ---- phase 1: stage A-half1(t+1); b23; MFMA (ti0-3, tj2-3)
    STAGE_A(cn, 1, ktn);
    #pragma unroll
    for (int tj = 0; tj < 2; ++tj)
      #pragma unroll
      for (int ks = 0; ks < 2; ++ks)
        b23[tj][ks] = ldb(&sBc[(wn + 16 * (tj + 2) + L) * 64 + ks * 32 + 8 * g]);
    __builtin_amdgcn_s_setprio(1);
    #pragma unroll
    for (int ti = 0; ti < 4; ++ti)
      #pragma unroll
      for (int tj = 0; tj < 2; ++tj) {
        acc[ti][tj + 2] = mfma16(a_[ti][0], b23[tj][0], acc[ti][tj + 2]);
        acc[ti][tj + 2] = mfma16(a_[ti][1], b23[tj][1], acc[ti][tj + 2]);
      }
    __builtin_amdgcn_s_setprio(0);
    __builtin_amdgcn_s_barrier();

    // ---- phase 2: stage B-half0(t+1); aHi; MFMA (ti4-7, tj2-3)
    STAGE_B(cn, 0, ktn);
    #pragma unroll
    for (int ti = 0; ti < 4; ++ti)
      #pragma unroll
      for (int ks = 0; ks < 2; ++ks)
        a_[ti][ks] = ldb(&sAc[(wm + 64 + 16 * ti + L) * 64 + ks * 32 + 8 * g]);
    __builtin_amdgcn_s_setprio(1);
    #pragma unroll
    for (int ti = 0; ti < 4; ++ti)
      #pragma unroll
      for (int tj = 0; tj < 2; ++tj) {
        acc[ti + 4][tj + 2] = mfma16(a_[ti][0], b23[tj][0], acc[ti + 4][tj + 2]);
        acc[ti + 4][tj + 2] = mfma16(a_[ti][1], b23[tj][1], acc[ti + 4][tj + 2]);
      }
    __builtin_amdgcn_s_setprio(0);
    __builtin_amdgcn_s_barrier();

    // ---- phase 3: stage B-half1(t+1); re-read b01; MFMA (ti4-7, tj0-1); boundary
    STAGE_B(cn, 1, ktn);
    #pragma unroll
    for (int tj = 0; tj < 2; ++tj)
      #pragma unroll
      for (int ks = 0; ks < 2; ++ks)
        b01[tj][ks] = ldb(&sBc[(wn + 16 * tj + L) * 64 + ks * 32 + 8 * g]);
    __builtin_amdgcn_s_setprio(1);
    #pragma unroll
    for (int ti = 0; ti < 4; ++ti)
      #pragma unroll
      for (int tj = 0; tj < 2; ++tj) {
        acc[ti + 4][tj] = mfma16(a_[ti][0], b01[tj][0], acc[ti + 4][tj]);
        acc[ti + 4][tj] = mfma16(a_[ti][1], b01[tj][1], acc[ti + 4][tj]);
      }
    __builtin_amdgcn_s_setprio(0);
    asm volatile("s_waitcnt vmcnt(0)" ::: "memory");  // tile t+1 fully resident
    __builtin_amdgcn_s_barrier();
    __builtin_amdgcn_sched_barrier(0);
  }
#undef STAGE_A
#undef STAGE_B

  // ---------------- epilogue: two 128-col phases through [256][136] LDS
  __syncthreads();
  float bs[4];
  #pragma unroll
  for (int tj = 0; tj < 4; ++tj) bs[tj] = bias[n0 + wn + 16 * tj + L];
  const int bg = m0 >> 11, s0 = m0 & 2047;
  const int row2 = tid >> 1, sh = tid & 1;
  const int hd = tid >> 2, q4 = tid & 3;
  #pragma unroll
  for (int p = 0; p < 2; ++p) {
    __syncthreads();
    if (((wv & 3) >> 1) == p) {
      #pragma unroll
      for (int ti = 0; ti < 8; ++ti)
        #pragma unroll
        for (int tj = 0; tj < 4; ++tj)
          #pragma unroll
          for (int r = 0; r < 4; ++r)
            qsm[(wm + 16 * ti + 4 * g + r) * 136 + (wn & 127) + 16 * tj + L] =
                f2b(acc[ti][tj][r] + bs[tj]);
    }
    __syncthreads();
    const int nb = n0 + p * 128;
    const int t3 = nb >> 11, hh = (nb & 2047) >> 7;
    if (t3 < 2) {
      u16* dst = (t3 == 0 ? qbuf : kbuf) + ((size_t)(bg * 16 + hh) * 2048 + s0) * 128;
      #pragma unroll
      for (int mm = 0; mm < 8; ++mm)
        *(u16x8*)&dst[(size_t)row2 * 128 + sh * 64 + 8 * mm] =
            *(const u16x8*)&qsm[row2 * 136 + sh * 64 + 8 * mm];
    } else {
      u16* dst = vbuf + (size_t)(bg * 16 + hh) * 128 * 2048 + s0;
      #pragma unroll
      for (int mm = 0; mm < 8; ++mm) {
        u16x8 v;
        #pragma unroll
        for (int jj = 0; jj < 8; ++jj) v[jj] = qsm[(q4 * 64 + 8 * mm + jj) * 136 + hd];
        *(u16x8*)&dst[(size_t)hd * 2048 + q4 * 64 + 8 * mm] = v;
      }
    }
  }
}

// ---------------------------------------------------------------- flash attention
// 512 thr / 8 waves; block covers 128 q-rows (wave wv owns q0 = qt*128 + wv*16).
// Branch-free inner loop; XCD-clustered 1D grid; setprio around MFMA clusters.
__global__ __launch_bounds__(512, 4) void attn(
    const u16* __restrict__ kbuf, const u16* __restrict__ vbuf,
    u16* __restrict__ qobuf) {
  u16* sK = dyn_smem;              // [128][136]
  u16* sV = dyn_smem + 128 * 136;  // [128][136]
  const int tid = threadIdx.x;
  const int lane = tid & 63, wv = tid >> 6;
  const int L = lane & 15, g = lane >> 4;
  const int bid = (int)blockIdx.x;
  const int logical = (bid & 7) * 128 + (bid >> 3);  // XCD-contiguous (1024 = 8*128)
  const int qt = 15 - (logical & 15);                // heavy blocks first
  const int bh_i = logical >> 4;                     // 0..63
  const int h = bh_i & 15, b = bh_i >> 4;
  const int q0 = qt * 128 + wv * 16;
  const size_t bh = (size_t)(b * 16 + h);
  const int row = tid >> 2, q4 = tid & 3;  // staging: 128 rows x 4 col-quarters

  const u16* Qp = qobuf + (bh * 2048 + q0) * 128;
  bf16x8 qf[4];
  #pragma unroll
  for (int ks = 0; ks < 4; ++ks) qf[ks] = ldb(&Qp[L * 128 + ks * 32 + 8 * g]);

  // log2-domain softmax: fold log2(e) into scale and slope, use exp2f directly
  const float LOG2E = 1.4426950408889634f;
  const float slope2 = exp2f(-0.5f * (float)(h + 1)) * LOG2E;
  const float scale2 = 0.08838834764831845f * LOG2E;
  float m_[4] = {-1e30f, -1e30f, -1e30f, -1e30f};
  float l_[4] = {0.f, 0.f, 0.f, 0.f};
  f32x4 oa[8] = {};
  u16* sP = sK + wv * 16 * 132;  // wave-private 16x132 region inside sK (8*2112 <= 17408)

  const int jmax = qt;  // keys needed up to qt*128+127
  for (int j = 0; j <= jmax; ++j) {
    __syncthreads();
    const u16* Kp = kbuf + (bh * 2048 + (size_t)j * 128) * 128;
    const u16* Vp = vbuf + bh * 128 * 2048 + j * 128;
    #pragma unroll
    for (int mm = 0; mm < 4; ++mm)
      *(u16x8*)&sK[row * 136 + q4 * 32 + 8 * mm] =
          *(const u16x8*)&Kp[row * 128 + q4 * 32 + 8 * mm];
    #pragma unroll
    for (int mm = 0; mm < 4; ++mm)
      *(u16x8*)&sV[row * 136 + q4 * 32 + 8 * mm] =
          *(const u16x8*)&Vp[(size_t)row * 2048 + q4 * 32 + 8 * mm];
    __syncthreads();

    f32x4 sc[8] = {};
    __builtin_amdgcn_s_setprio(1);
    #pragma unroll
    for (int ks = 0; ks < 4; ++ks)
      #pragma unroll
      for (int tc = 0; tc < 8; ++tc) {
        bf16x8 kf = ldb(&sK[(16 * tc + L) * 136 + ks * 32 + 8 * g]);
        sc[tc] = mfma16(qf[ks], kf, sc[tc]);
      }
    __builtin_amdgcn_s_setprio(0);

    float tmax[4] = {-1e30f, -1e30f, -1e30f, -1e30f};
    const int kbase = j * 128 + L;
    const bool need_mask = (j * 128 + 127) > q0;
    #pragma unroll
    for (int tc = 0; tc < 8; ++tc) {
      const int kpos = kbase + 16 * tc;
      const float ab = slope2 * (float)(kpos - 2047);
      #pragma unroll
      for (int r = 0; r < 4; ++r) {
        float s = sc[tc][r] * scale2 + ab;
        if (need_mask && kpos > q0 + 4 * g + r) s = -1e30f;
        sc[tc][r] = s;
        tmax[r] = fmaxf(tmax[r], s);
      }
    }
    #pragma unroll
    for (int r = 0; r < 4; ++r) {
      #pragma unroll
      for (int d = 1; d < 16; d <<= 1)
        tmax[r] = fmaxf(tmax[r], __shfl_xor(tmax[r], d, 64));
    }
    float al[4], ps[4];
    #pragma unroll
    for (int r = 0; r < 4; ++r) {
      float mn = fmaxf(m_[r], tmax[r]);
      al[r] = exp2f(m_[r] - mn);
      m_[r] = mn;
      ps[r] = 0.f;
    }
    #pragma unroll
    for (int tc = 0; tc < 8; ++tc)
      #pragma unroll
      for (int r = 0; r < 4; ++r) {
        float p = exp2f(sc[tc][r] - m_[r]);
        sc[tc][r] = p;
        ps[r] += p;
      }
    #pragma unroll
    for (int r = 0; r < 4; ++r) {
      #pragma unroll
      for (int d = 1; d < 16; d <<= 1) ps[r] += __shfl_xor(ps[r], d, 64);
      l_[r] = l_[r] * al[r] + ps[r];
    }
    #pragma unroll
    for (int tn = 0; tn < 8; ++tn)
      #pragma unroll
      for (int r = 0; r < 4; ++r) oa[tn][r] *= al[r];

    __syncthreads();
    #pragma unroll
    for (int tc = 0; tc < 8; ++tc)
      #pragma unroll
      for (int r = 0; r < 4; ++r)
        sP[(4 * g + r) * 132 + 16 * tc + L] = f2b(sc[tc][r]);

    __builtin_amdgcn_s_setprio(1);
    #pragma unroll
    for (int ks = 0; ks < 4; ++ks) {
      bf16x8 pf = ldb(&sP[L * 132 + ks * 32 + 8 * g]);
      #pragma unroll
      for (int tn = 0; tn < 8; ++tn) {
        bf16x8 vf = ldb(&sV[(16 * tn + L) * 136 + ks * 32 + 8 * g]);
        oa[tn] = mfma16(pf, vf, oa[tn]);
      }
    }
    __builtin_amdgcn_s_setprio(0);
  }

  u16* Op = qobuf + (bh * 2048 + q0) * 128;
  float inv[4];
  #pragma unroll
  for (int r = 0; r < 4; ++r) inv[r] = 1.0f / l_[r];
  #pragma unroll
  for (int tn = 0; tn < 8; ++tn)
    #pragma unroll
    for (int r = 0; r < 4; ++r)
      Op[(4 * g + r) * 128 + 16 * tn + L] = f2b(oa[tn][r] * inv[r]);
}

// ---------------------------------------------------------------- GEMM2: out proj
// out[8192,2048] = O @ Wout + b_out. 128x256x32 tiles (m97 structure),
// 4 waves, 4x8 frags/wave, global_load_lds staging, direct fp32 epilogue.
// Flat 512-block grid, XCD-bijective: wg = (bid&7)*64 + bid>>3; mt = wg>>3, nt = wg&7.
__global__ __launch_bounds__(256, 2) void gemm_out(
    const u16* __restrict__ obuf, const u16* __restrict__ wT,
    const float* __restrict__ bias, float* __restrict__ out) {
  __shared__ u16 smem[128 * 32 + 256 * 32];  // sA[128x32] + sB[256x32] = 24KB
  u16* sA = smem;
  u16* sB = smem + 128 * 32;
  const int tid = threadIdx.x;
  const int lane = tid & 63, wv = tid >> 6;
  const int L = lane & 15, g = lane >> 4;
  const int wm = (wv >> 1) * 64, wn = (wv & 1) * 128;
  const int bid = (int)blockIdx.x;
  const int wg = (bid & 7) * 64 + (bid >> 3);       // bijective XCD cluster (512=8*64)
  const int m0 = (wg >> 3) * 128, n0 = (wg & 7) * 256;
  const int bg = m0 >> 11, s0 = m0 & 2047;

  // staging: lane l -> row +(l>>2), col (l&3)*8 within the 32-wide k-window
  const int lr = lane >> 2, lc = (lane & 3) * 8;
  // A: O in [B,H,S,HD]; k = kt*32 + lc -> head kt>>2, within-head col (kt&3)*32 + lc
  const u16* aA0 = obuf + ((size_t)(bg * 16) * 2048 + s0 + 32 * wv + lr) * 128 + lc;
  const u16* aA1 = aA0 + (size_t)16 * 128;
  const u16* gB0 = wT + (size_t)(n0 + 64 * wv + lr) * 2048 + lc;
  const u16* gB1 = gB0 + (size_t)16 * 2048;
  const u16* gB2 = gB0 + (size_t)32 * 2048;
  const u16* gB3 = gB0 + (size_t)48 * 2048;
  u16* lA0 = &sA[1024 * wv];
  u16* lA1 = &sA[1024 * wv + 512];
  u16* lB0 = &sB[2048 * wv];
  u16* lB1 = &sB[2048 * wv + 512];
  u16* lB2 = &sB[2048 * wv + 1024];
  u16* lB3 = &sB[2048 * wv + 1536];

  f32x4 acc[4][8] = {};

  for (int kt = 0; kt < 64; ++kt) {
    __syncthreads();
    const size_t aoff = (size_t)(kt >> 2) * (2048 * 128) + (size_t)((kt & 3) * 32);
    g2l16(aA0 + aoff, lA0); g2l16(aA1 + aoff, lA1);
    g2l16(gB0, lB0); g2l16(gB1, lB1); g2l16(gB2, lB2); g2l16(gB3, lB3);
    gB0 += 32; gB1 += 32; gB2 += 32; gB3 += 32;
    __syncthreads();

    bf16x8 af[4], bfr[8];
    #pragma unroll
    for (int t = 0; t < 4; ++t) af[t] = ldb(&sA[(wm + 16 * t + L) * 32 + 8 * g]);
    #pragma unroll
    for (int t = 0; t < 8; ++t) bfr[t] = ldb(&sB[(wn + 16 * t + L) * 32 + 8 * g]);
    #pragma unroll
    for (int ti = 0; ti < 4; ++ti)
      #pragma unroll
      for (int tj = 0; tj < 8; ++tj)
        acc[ti][tj] = mfma16(af[ti], bfr[tj], acc[ti][tj]);
  }

  float bs[8];
  #pragma unroll
  for (int tj = 0; tj < 8; ++tj) bs[tj] = bias[n0 + wn + 16 * tj + L];
  #pragma unroll
  for (int ti = 0; ti < 4; ++ti)
    #pragma unroll
    for (int tj = 0; tj < 8; ++tj)
      #pragma unroll
      for (int r = 0; r < 4; ++r)
        out[(size_t)(m0 + wm + 16 * ti + 4 * g + r) * 2048 + n0 + wn + 16 * tj + L] =
            acc[ti][tj][r] + bs[tj];
}

// ---------------------------------------------------------------- launch
extern "C" void kernel_launch(void* const* d_in, const int* in_sizes, int n_in,
                              void* d_out, int out_size, void* d_ws, size_t ws_size,
                              hipStream_t stream) {
  const float* x    = (const float*)d_in[0];
  const float* Wqkv = (const float*)d_in[1];
  const float* bqkv = (const float*)d_in[2];
  const float* Wout = (const float*)d_in[3];
  const float* bout = (const float*)d_in[4];
  float* out = (float*)d_out;

  char* ws = (char*)d_ws;
  u16* wqkvT = (u16*)(ws + 0);           // 6144*2048*2  = 25165824
  u16* woutT = (u16*)(ws + 25165824);    // 2048*2048*2  =  8388608
  u16* qbuf  = (u16*)(ws + 33554432);    // 4*16*2048*128*2 = 33554432 (becomes O)
  u16* kbuf  = (u16*)(ws + 67108864);
  u16* vbuf  = (u16*)(ws + 100663296);   // transposed [B,H,HD,S]; total 128 MiB

  // x in bf16 lives in d_out (32 MiB of 64 MiB); gemm_out overwrites all of d_out later
  u16* xb = (u16*)d_out;

  transpose_cvt<<<dim3(192, 64), 256, 0, stream>>>(Wqkv, wqkvT, 2048, 6144);
  transpose_cvt<<<dim3(64, 64), 256, 0, stream>>>(Wout, woutT, 2048, 2048);
  cvt_bf16<<<8192, 256, 0, stream>>>(x, xb);
  gemm_qkv<<<dim3(768), 512, 131072, stream>>>(xb, wqkvT, bqkv, qbuf, kbuf, vbuf);
  attn<<<dim3(1024), 512, 69632, stream>>>(kbuf, vbuf, qbuf);
  gemm_out<<<dim3(512), 256, 0, stream>>>(qbuf, woutT, bout, out);
}